// Round 2
// baseline (679.638 us; speedup 1.0000x reference)
//
#include <hip/hip_runtime.h>

typedef _Float16 half8_t __attribute__((ext_vector_type(8)));
typedef float f32x4 __attribute__((ext_vector_type(4)));

#define B_ 128
#define N_ 4096
#define H_ 128
#define P_ 128
#define CCH 16                       // chunks per batch row
#define ROWS_PER_CHUNK (N_ / CCH)    // 256
#define TILES 4                      // 64-row tiles per chunk (16 rows/wave/iter)

// workspace layout (float offsets)
#define OFF_SCALES 0          // [0]=sv [1]=sq [2]=sa
#define OFF_WA     16         // 128 floats: normalized wa
#define OFF_QPC    256        // B*P floats: q_proj + bq + bv
#define OFF_BPACK  16640      // 16384 f16 = 8192 float slots: MFMA-packed Wv^T
#define OFF_LOGITS 24832      // B*N floats
#define OFF_PART   549120     // B*CCH*132 floats: per-(b,chunk) m,l,o[128],pad2
#define OFF_FIN    819456     // [b]=m_b, [B_+b]=1/l_b

__device__ __forceinline__ float block_reduce_sum(float val, float* red, int tid) {
    red[tid] = val;
    __syncthreads();
    for (int s = 128; s > 0; s >>= 1) {
        if (tid < s) red[tid] += red[tid + s];
        __syncthreads();
    }
    float r = red[0];
    __syncthreads();
    return r;
}

// ---------- K0a: norms, scales, normalized wa, MFMA-packed Wv ----------
__global__ __launch_bounds__(256) void k0a_prep(
    const float* __restrict__ Wv, const float* __restrict__ gv,
    const float* __restrict__ Wq, const float* __restrict__ gq,
    const float* __restrict__ Wa, const float* __restrict__ ga,
    float* __restrict__ ws)
{
    __shared__ float red[256];
    __shared__ float s_sv, s_sa;
    const int tid = threadIdx.x;

    float sv2 = 0.f, sq2 = 0.f, sa2 = 0.f;
    for (int i = tid; i < P_ * H_; i += 256) {
        float x = Wv[i]; sv2 += x * x;
        float y = Wq[i]; sq2 += y * y;
    }
    if (tid < P_) { float z = Wa[tid]; sa2 = z * z; }

    float nv2 = block_reduce_sum(sv2, red, tid);
    float nq2 = block_reduce_sum(sq2, red, tid);
    float na2 = block_reduce_sum(sa2, red, tid);

    if (tid == 0) {
        float sv = gv[0] / sqrtf(nv2);
        float sq = gq[0] / sqrtf(nq2);
        float sa = ga[0] / sqrtf(na2);
        ws[OFF_SCALES + 0] = sv;
        ws[OFF_SCALES + 1] = sq;
        ws[OFF_SCALES + 2] = sa;
        s_sv = sv; s_sa = sa;
    }
    __syncthreads();

    const float sv = s_sv, sa = s_sa;
    // Bpack[s]: s = ((kk*8+pt)*64 + L)*8 + j  ->  Wv[p][h]*sv with
    // p = pt*16 + (L&15), h = kk*32 + (L>>4)*8 + j   (MFMA B-fragment order)
    _Float16* bp = (_Float16*)(ws + OFF_BPACK);
    for (int s = tid; s < 16384; s += 256) {
        int j  = s & 7;
        int L  = (s >> 3) & 63;
        int pt = (s >> 9) & 7;
        int kk = s >> 12;
        int p = pt * 16 + (L & 15);
        int h = kk * 32 + (L >> 4) * 8 + j;
        bp[s] = (_Float16)(Wv[p * H_ + h] * sv);
    }
    if (tid < P_) ws[OFF_WA + tid] = Wa[tid] * sa;
}

// ---------- K0b: q_proj[b][p] = sq*(q[b]·Wq[p]) + bq[p] + bv[p] ----------
__global__ __launch_bounds__(128) void k0b_qproj(
    const float* __restrict__ q, const float* __restrict__ Wq,
    const float* __restrict__ bq, const float* __restrict__ bv,
    float* __restrict__ ws)
{
    const int b = blockIdx.x, p = threadIdx.x;
    const float sq = ws[OFF_SCALES + 1];
    const float* qr = q + b * H_;
    const float* wr = Wq + p * H_;
    float acc = 0.f;
#pragma unroll 8
    for (int h = 0; h < H_; ++h) acc += qr[h] * wr[h];
    ws[OFF_QPC + b * P_ + p] = acc * sq + bq[p] + bv[p];
}

// ---------- K1: one pass over v; wave-private online softmax, zero barriers
// ---------- in the K-loop; o accumulated from the register-held tile.
__global__ __launch_bounds__(256, 4) void k1_main(
    const float* __restrict__ v, const float* __restrict__ mask,
    const float* __restrict__ ba, float* __restrict__ ws)
{
    const int c = blockIdx.x;   // chunk
    const int b = blockIdx.y;   // batch
    const int tid = threadIdx.x;
    const int lane = tid & 63;
    const int w = tid >> 6;     // wave id 0..3

    __shared__ __align__(16) _Float16 Bl[16384];   // 32 KB packed B-frags
    __shared__ float qpcs[P_];
    __shared__ float was[P_];
    __shared__ float obuf[4][P_];                  // per-wave o partials
    __shared__ float mbuf[4], lbuf[4];

    {
        const uint4* src = (const uint4*)(ws + OFF_BPACK);
        uint4* dst = (uint4*)Bl;
#pragma unroll
        for (int i = 0; i < 8; ++i) dst[tid + i * 256] = src[tid + i * 256];
        if (tid < P_) {
            qpcs[tid] = ws[OFF_QPC + b * P_ + tid];
            was[tid]  = ws[OFF_WA + tid];
        }
    }
    const float ba0 = ba[0];
    __syncthreads();

    const int rloc = lane & 15;        // v-row owned by this lane (A-frag m)
    const int grp  = lane >> 4;        // 16-lane group id 0..3
    const int colb = grp * 8;          // col sub-block within each 32-col slice

    float m_w = -1e30f, l_w = 0.f;
    float o32[32];
#pragma unroll
    for (int j = 0; j < 32; ++j) o32[j] = 0.f;

    for (int it = 0; it < TILES; ++it) {
        const int n0w = c * ROWS_PER_CHUNK + it * 64 + w * 16;

        // ---- load 16x128 tile: lane holds row rloc, cols {kk*32+colb .. +7}
        const float* vrow = v + ((size_t)b * N_ + n0w + rloc) * H_;
        float vf[32];
        half8_t af[4];
#pragma unroll
        for (int kk = 0; kk < 4; ++kk) {
            const float4* p4 = (const float4*)(vrow + kk * 32 + colb);
            float4 f0 = p4[0], f1 = p4[1];
            vf[kk * 8 + 0] = f0.x; vf[kk * 8 + 1] = f0.y;
            vf[kk * 8 + 2] = f0.z; vf[kk * 8 + 3] = f0.w;
            vf[kk * 8 + 4] = f1.x; vf[kk * 8 + 5] = f1.y;
            vf[kk * 8 + 6] = f1.z; vf[kk * 8 + 7] = f1.w;
            half8_t a;
            a[0] = (_Float16)f0.x; a[1] = (_Float16)f0.y;
            a[2] = (_Float16)f0.z; a[3] = (_Float16)f0.w;
            a[4] = (_Float16)f1.x; a[5] = (_Float16)f1.y;
            a[6] = (_Float16)f1.z; a[7] = (_Float16)f1.w;
            af[kk] = a;
        }

        // ---- v_proj via MFMA + relu·wa partial logits
        float lp[4];
        {
            const float qv0 = qpcs[rloc];          // p-col = pt*16 + rloc
            lp[0] = lp[1] = lp[2] = lp[3] = 0.f;
#pragma unroll
            for (int pt = 0; pt < 8; ++pt) {
                const int p = pt * 16 + rloc;
                const float qv = qpcs[p];
                f32x4 acc = {qv, qv, qv, qv};      // fold q_proj into C init
#pragma unroll
                for (int kk = 0; kk < 4; ++kk) {
                    half8_t bf = *(const half8_t*)&Bl[(((kk * 8 + pt) * 64) + lane) * 8];
                    acc = __builtin_amdgcn_mfma_f32_16x16x32_f16(af[kk], bf, acc, 0, 0, 0);
                }
                const float wv = was[p];
#pragma unroll
                for (int r = 0; r < 4; ++r)
                    lp[r] += fmaxf(acc[r], 0.f) * wv;
            }
            (void)qv0;
        }
        // reduce over the 16 p-cols (lanes differing in bits 0-3)
#pragma unroll
        for (int m = 1; m <= 8; m <<= 1) {
#pragma unroll
            for (int r = 0; r < 4; ++r) lp[r] += __shfl_xor(lp[r], m, 64);
        }
        // lp[r] is now the logit of row (grp*4 + r); add bias + mask
#pragma unroll
        for (int r = 0; r < 4; ++r) {
            const float mk = mask[(size_t)b * N_ + n0w + grp * 4 + r];
            lp[r] += ba0 + (1.0f - mk) * (-10000.0f);
        }

        // transpose: lg_me = logit of row rloc (the row this lane HOLDS)
        const int srcl = (rloc >> 2) << 4;
        float t0 = __shfl(lp[0], srcl, 64);
        float t1 = __shfl(lp[1], srcl, 64);
        float t2 = __shfl(lp[2], srcl, 64);
        float t3 = __shfl(lp[3], srcl, 64);
        float a01 = (rloc & 1) ? t1 : t0;
        float a23 = (rloc & 1) ? t3 : t2;
        float lg_me = (rloc & 2) ? a23 : a01;

        // store logits (lanes 0..15 cover rows n0w..n0w+15, coalesced)
        if (lane < 16) ws[OFF_LOGITS + (size_t)b * N_ + n0w + lane] = lg_me;

        // wave max over its 16 rows
        float mt = fmaxf(fmaxf(lp[0], lp[1]), fmaxf(lp[2], lp[3]));
        mt = fmaxf(mt, __shfl_xor(mt, 16, 64));
        mt = fmaxf(mt, __shfl_xor(mt, 32, 64));

        // wave-private online softmax update
        const float mn = fmaxf(m_w, mt);
        const float alpha = __expf(m_w - mn);
        const float wme = __expf(lg_me - mn);
        float s = wme;
#pragma unroll
        for (int m = 1; m <= 8; m <<= 1) s += __shfl_xor(s, m, 64);
        l_w = l_w * alpha + s;
        m_w = mn;

        if (alpha != 1.0f) {
#pragma unroll
            for (int j = 0; j < 32; ++j) o32[j] *= alpha;
        }
#pragma unroll
        for (int j = 0; j < 32; ++j) o32[j] += wme * vf[j];
    }

    // ---- intra-wave o reduction over the 16 rows (lanes, bits 0-3)
#pragma unroll
    for (int m = 1; m <= 8; m <<= 1) {
#pragma unroll
        for (int j = 0; j < 32; ++j) o32[j] += __shfl_xor(o32[j], m, 64);
    }
    // every lane in group grp now holds o for cols {kk*32 + grp*8 + jj}
    // each lane writes 2 of the 32 values
    {
        const int j0 = rloc * 2;
#pragma unroll
        for (int u = 0; u < 2; ++u) {
            const int j = j0 + u;
            obuf[w][(j >> 3) * 32 + colb + (j & 7)] = o32[j];
        }
        if (lane == 0) { mbuf[w] = m_w; lbuf[w] = l_w; }
    }
    __syncthreads();

    // ---- merge 4 wave partials -> chunk partial
    float* part = ws + OFF_PART + ((size_t)b * CCH + c) * 132;
    if (tid < P_) {
        const float mb = fmaxf(fmaxf(mbuf[0], mbuf[1]), fmaxf(mbuf[2], mbuf[3]));
        float lb = 0.f, oh = 0.f;
#pragma unroll
        for (int ww = 0; ww < 4; ++ww) {
            const float e = __expf(mbuf[ww] - mb);
            lb += e * lbuf[ww];
            oh += e * obuf[ww][tid];
        }
        part[2 + tid] = oh;
        if (tid == 0) { part[0] = mb; part[1] = lb; }
    }
}

// ---------- K2a: combine chunk partials -> att, global m/l ----------
__global__ __launch_bounds__(128) void k2a_combine(
    float* __restrict__ ws, float* __restrict__ out)
{
    const int b = blockIdx.x, h = threadIdx.x;
    const float* part = ws + OFF_PART + (size_t)b * CCH * 132;
    float m = -1e30f;
#pragma unroll
    for (int c = 0; c < CCH; ++c) m = fmaxf(m, part[c * 132]);
    float l = 0.f, a = 0.f;
#pragma unroll
    for (int c = 0; c < CCH; ++c) {
        const float e = __expf(part[c * 132] - m);
        l += e * part[c * 132 + 1];
        a += e * part[c * 132 + 2 + h];
    }
    out[b * H_ + h] = a / l;
    if (h == 0) {
        ws[OFF_FIN + b] = m;
        ws[OFF_FIN + B_ + b] = 1.0f / l;
    }
}

// ---------- K2b: w[b,n] = exp(logit - m_b) / l_b ----------
__global__ __launch_bounds__(256) void k2b_weights(
    const float* __restrict__ ws, float* __restrict__ out)
{
    const int idx = blockIdx.x * 256 + threadIdx.x;  // < B_*N_
    const int b = idx >> 12;
    const float lg = ws[OFF_LOGITS + idx];
    out[B_ * H_ + idx] = __expf(lg - ws[OFF_FIN + b]) * ws[OFF_FIN + B_ + b];
}

extern "C" void kernel_launch(void* const* d_in, const int* in_sizes, int n_in,
                              void* d_out, int out_size, void* d_ws, size_t ws_size,
                              hipStream_t stream) {
    const float* v    = (const float*)d_in[0];
    const float* q    = (const float*)d_in[1];
    const float* mask = (const float*)d_in[2];
    const float* Wv   = (const float*)d_in[3];
    const float* bv   = (const float*)d_in[4];
    const float* gv   = (const float*)d_in[5];
    const float* Wq   = (const float*)d_in[6];
    const float* bq   = (const float*)d_in[7];
    const float* gq   = (const float*)d_in[8];
    const float* Wa   = (const float*)d_in[9];
    const float* ba   = (const float*)d_in[10];
    const float* ga   = (const float*)d_in[11];
    float* out = (float*)d_out;
    float* ws  = (float*)d_ws;

    k0a_prep<<<1, 256, 0, stream>>>(Wv, gv, Wq, gq, Wa, ga, ws);
    k0b_qproj<<<B_, 128, 0, stream>>>(q, Wq, bq, bv, ws);
    k1_main<<<dim3(CCH, B_), 256, 0, stream>>>(v, mask, ba, ws);
    k2a_combine<<<B_, 128, 0, stream>>>(ws, out);
    k2b_weights<<<(B_ * N_) / 256, 256, 0, stream>>>(ws, out);
}

// Round 3
// 460.635 us; speedup vs baseline: 1.4754x; 1.4754x over previous
//
#include <hip/hip_runtime.h>

typedef _Float16 half8_t __attribute__((ext_vector_type(8)));
typedef float f32x4 __attribute__((ext_vector_type(4)));

#define B_ 128
#define N_ 4096
#define H_ 128
#define P_ 128
#define CCH 16                       // chunks per batch row
#define ROWS_PER_CHUNK (N_ / CCH)    // 256
#define TILES 4                      // 64-row tiles per chunk (16 rows/wave/iter)

// workspace layout (float offsets)
#define OFF_SCALES 0          // [0]=sv [1]=sq [2]=sa
#define OFF_WA     16         // 128 floats: normalized wa
#define OFF_QPC    256        // B*P floats: q_proj + bq + bv
#define OFF_BPACK  16640      // 16384 f16 = 8192 float slots: MFMA-packed Wv^T
#define OFF_LOGITS 24832      // B*N floats
#define OFF_PART   549120     // B*CCH*132 floats: per-(b,chunk) m,l,o[128],pad2
#define OFF_FIN    819456     // [b]=m_b, [B_+b]=1/l_b

__device__ __forceinline__ float block_reduce_sum(float val, float* red, int tid) {
    red[tid] = val;
    __syncthreads();
    for (int s = 128; s > 0; s >>= 1) {
        if (tid < s) red[tid] += red[tid + s];
        __syncthreads();
    }
    float r = red[0];
    __syncthreads();
    return r;
}

// ---------- K0a: norms, scales, normalized wa, MFMA-packed Wv ----------
__global__ __launch_bounds__(256) void k0a_prep(
    const float* __restrict__ Wv, const float* __restrict__ gv,
    const float* __restrict__ Wq, const float* __restrict__ gq,
    const float* __restrict__ Wa, const float* __restrict__ ga,
    float* __restrict__ ws)
{
    __shared__ float red[256];
    __shared__ float s_sv, s_sa;
    const int tid = threadIdx.x;

    float sv2 = 0.f, sq2 = 0.f, sa2 = 0.f;
    for (int i = tid; i < P_ * H_; i += 256) {
        float x = Wv[i]; sv2 += x * x;
        float y = Wq[i]; sq2 += y * y;
    }
    if (tid < P_) { float z = Wa[tid]; sa2 = z * z; }

    float nv2 = block_reduce_sum(sv2, red, tid);
    float nq2 = block_reduce_sum(sq2, red, tid);
    float na2 = block_reduce_sum(sa2, red, tid);

    if (tid == 0) {
        float sv = gv[0] / sqrtf(nv2);
        float sq = gq[0] / sqrtf(nq2);
        float sa = ga[0] / sqrtf(na2);
        ws[OFF_SCALES + 0] = sv;
        ws[OFF_SCALES + 1] = sq;
        ws[OFF_SCALES + 2] = sa;
        s_sv = sv; s_sa = sa;
    }
    __syncthreads();

    const float sv = s_sv, sa = s_sa;
    // Bpack[s]: s = ((kk*8+pt)*64 + L)*8 + j  ->  Wv[p][h]*sv with
    // p = pt*16 + (L&15), h = kk*32 + (L>>4)*8 + j   (MFMA B-fragment order)
    _Float16* bp = (_Float16*)(ws + OFF_BPACK);
    for (int s = tid; s < 16384; s += 256) {
        int j  = s & 7;
        int L  = (s >> 3) & 63;
        int pt = (s >> 9) & 7;
        int kk = s >> 12;
        int p = pt * 16 + (L & 15);
        int h = kk * 32 + (L >> 4) * 8 + j;
        bp[s] = (_Float16)(Wv[p * H_ + h] * sv);
    }
    if (tid < P_) ws[OFF_WA + tid] = Wa[tid] * sa;
}

// ---------- K0b: q_proj[b][p] = sq*(q[b]·Wq[p]) + bq[p] + bv[p] ----------
__global__ __launch_bounds__(128) void k0b_qproj(
    const float* __restrict__ q, const float* __restrict__ Wq,
    const float* __restrict__ bq, const float* __restrict__ bv,
    float* __restrict__ ws)
{
    const int b = blockIdx.x, p = threadIdx.x;
    const float sq = ws[OFF_SCALES + 1];
    const float* qr = q + b * H_;
    const float* wr = Wq + p * H_;
    float acc = 0.f;
#pragma unroll 8
    for (int h = 0; h < H_; ++h) acc += qr[h] * wr[h];
    ws[OFF_QPC + b * P_ + p] = acc * sq + bq[p] + bv[p];
}

// ---------- K1: one pass over v; wave-private online softmax, zero barriers
// ---------- in the K-loop; o accumulated from the register-held tile.
// NOTE: no min-waves clause — R2's (256,4) capped VGPRs at 64 and caused
// ~800 MB of scratch spill traffic (WRITE_SIZE 337 MB). ~110 live VGPRs here.
__global__ __launch_bounds__(256) void k1_main(
    const float* __restrict__ v, const float* __restrict__ mask,
    const float* __restrict__ ba, float* __restrict__ ws)
{
    const int c = blockIdx.x;   // chunk
    const int b = blockIdx.y;   // batch
    const int tid = threadIdx.x;
    const int lane = tid & 63;
    const int w = tid >> 6;     // wave id 0..3

    __shared__ __align__(16) _Float16 Bl[16384];   // 32 KB packed B-frags
    __shared__ float qpcs[P_];
    __shared__ float was[P_];
    __shared__ float obuf[4][P_];                  // per-wave o partials
    __shared__ float mbuf[4], lbuf[4];

    {
        const uint4* src = (const uint4*)(ws + OFF_BPACK);
        uint4* dst = (uint4*)Bl;
#pragma unroll
        for (int i = 0; i < 8; ++i) dst[tid + i * 256] = src[tid + i * 256];
        if (tid < P_) {
            qpcs[tid] = ws[OFF_QPC + b * P_ + tid];
            was[tid]  = ws[OFF_WA + tid];
        }
    }
    const float ba0 = ba[0];
    __syncthreads();

    const int rloc = lane & 15;        // v-row owned by this lane (A-frag m)
    const int grp  = lane >> 4;        // 16-lane group id 0..3
    const int colb = grp * 8;          // col sub-block within each 32-col slice

    float m_w = -1e30f, l_w = 0.f;
    float o32[32];
#pragma unroll
    for (int j = 0; j < 32; ++j) o32[j] = 0.f;

    for (int it = 0; it < TILES; ++it) {
        const int n0w = c * ROWS_PER_CHUNK + it * 64 + w * 16;

        // ---- load 16x128 tile: lane holds row rloc, cols {kk*32+colb .. +7}
        const float* vrow = v + ((size_t)b * N_ + n0w + rloc) * H_;
        float vf[32];
        half8_t af[4];
#pragma unroll
        for (int kk = 0; kk < 4; ++kk) {
            const float4* p4 = (const float4*)(vrow + kk * 32 + colb);
            float4 f0 = p4[0], f1 = p4[1];
            vf[kk * 8 + 0] = f0.x; vf[kk * 8 + 1] = f0.y;
            vf[kk * 8 + 2] = f0.z; vf[kk * 8 + 3] = f0.w;
            vf[kk * 8 + 4] = f1.x; vf[kk * 8 + 5] = f1.y;
            vf[kk * 8 + 6] = f1.z; vf[kk * 8 + 7] = f1.w;
            half8_t a;
            a[0] = (_Float16)f0.x; a[1] = (_Float16)f0.y;
            a[2] = (_Float16)f0.z; a[3] = (_Float16)f0.w;
            a[4] = (_Float16)f1.x; a[5] = (_Float16)f1.y;
            a[6] = (_Float16)f1.z; a[7] = (_Float16)f1.w;
            af[kk] = a;
        }

        // ---- v_proj via MFMA + relu·wa partial logits
        float lp[4];
        lp[0] = lp[1] = lp[2] = lp[3] = 0.f;
#pragma unroll
        for (int pt = 0; pt < 8; ++pt) {
            const int p = pt * 16 + rloc;
            const float qv = qpcs[p];
            f32x4 acc = {qv, qv, qv, qv};      // fold q_proj into C init
#pragma unroll
            for (int kk = 0; kk < 4; ++kk) {
                half8_t bf = *(const half8_t*)&Bl[(((kk * 8 + pt) * 64) + lane) * 8];
                acc = __builtin_amdgcn_mfma_f32_16x16x32_f16(af[kk], bf, acc, 0, 0, 0);
            }
            const float wv = was[p];
#pragma unroll
            for (int r = 0; r < 4; ++r)
                lp[r] += fmaxf(acc[r], 0.f) * wv;
        }
        // reduce over the 16 p-cols (lanes differing in bits 0-3)
#pragma unroll
        for (int m = 1; m <= 8; m <<= 1) {
#pragma unroll
            for (int r = 0; r < 4; ++r) lp[r] += __shfl_xor(lp[r], m, 64);
        }
        // lp[r] is now the logit of row (grp*4 + r); add bias + mask
#pragma unroll
        for (int r = 0; r < 4; ++r) {
            const float mk = mask[(size_t)b * N_ + n0w + grp * 4 + r];
            lp[r] += ba0 + (1.0f - mk) * (-10000.0f);
        }

        // transpose: lg_me = logit of row rloc (the row this lane HOLDS)
        const int srcl = (rloc >> 2) << 4;
        float t0 = __shfl(lp[0], srcl, 64);
        float t1 = __shfl(lp[1], srcl, 64);
        float t2 = __shfl(lp[2], srcl, 64);
        float t3 = __shfl(lp[3], srcl, 64);
        float a01 = (rloc & 1) ? t1 : t0;
        float a23 = (rloc & 1) ? t3 : t2;
        float lg_me = (rloc & 2) ? a23 : a01;

        // store logits (lanes 0..15 cover rows n0w..n0w+15, coalesced)
        if (lane < 16) ws[OFF_LOGITS + (size_t)b * N_ + n0w + lane] = lg_me;

        // wave max over its 16 rows
        float mt = fmaxf(fmaxf(lp[0], lp[1]), fmaxf(lp[2], lp[3]));
        mt = fmaxf(mt, __shfl_xor(mt, 16, 64));
        mt = fmaxf(mt, __shfl_xor(mt, 32, 64));

        // wave-private online softmax update
        const float mn = fmaxf(m_w, mt);
        const float alpha = __expf(m_w - mn);
        const float wme = __expf(lg_me - mn);
        float s = wme;
#pragma unroll
        for (int m = 1; m <= 8; m <<= 1) s += __shfl_xor(s, m, 64);
        l_w = l_w * alpha + s;
        m_w = mn;

        if (alpha != 1.0f) {
#pragma unroll
            for (int j = 0; j < 32; ++j) o32[j] *= alpha;
        }
#pragma unroll
        for (int j = 0; j < 32; ++j) o32[j] += wme * vf[j];
    }

    // ---- intra-wave o reduction over the 16 rows (lanes, bits 0-3)
#pragma unroll
    for (int m = 1; m <= 8; m <<= 1) {
#pragma unroll
        for (int j = 0; j < 32; ++j) o32[j] += __shfl_xor(o32[j], m, 64);
    }
    // every lane in group grp now holds o for cols {kk*32 + grp*8 + jj}
    // each lane writes 2 of the 32 values
    {
        const int j0 = rloc * 2;
#pragma unroll
        for (int u = 0; u < 2; ++u) {
            const int j = j0 + u;
            obuf[w][(j >> 3) * 32 + colb + (j & 7)] = o32[j];
        }
        if (lane == 0) { mbuf[w] = m_w; lbuf[w] = l_w; }
    }
    __syncthreads();

    // ---- merge 4 wave partials -> chunk partial
    float* part = ws + OFF_PART + ((size_t)b * CCH + c) * 132;
    if (tid < P_) {
        const float mb = fmaxf(fmaxf(mbuf[0], mbuf[1]), fmaxf(mbuf[2], mbuf[3]));
        float lb = 0.f, oh = 0.f;
#pragma unroll
        for (int ww = 0; ww < 4; ++ww) {
            const float e = __expf(mbuf[ww] - mb);
            lb += e * lbuf[ww];
            oh += e * obuf[ww][tid];
        }
        part[2 + tid] = oh;
        if (tid == 0) { part[0] = mb; part[1] = lb; }
    }
}

// ---------- K2a: combine chunk partials -> att, global m/l ----------
__global__ __launch_bounds__(128) void k2a_combine(
    float* __restrict__ ws, float* __restrict__ out)
{
    const int b = blockIdx.x, h = threadIdx.x;
    const float* part = ws + OFF_PART + (size_t)b * CCH * 132;
    float m = -1e30f;
#pragma unroll
    for (int c = 0; c < CCH; ++c) m = fmaxf(m, part[c * 132]);
    float l = 0.f, a = 0.f;
#pragma unroll
    for (int c = 0; c < CCH; ++c) {
        const float e = __expf(part[c * 132] - m);
        l += e * part[c * 132 + 1];
        a += e * part[c * 132 + 2 + h];
    }
    out[b * H_ + h] = a / l;
    if (h == 0) {
        ws[OFF_FIN + b] = m;
        ws[OFF_FIN + B_ + b] = 1.0f / l;
    }
}

// ---------- K2b: w[b,n] = exp(logit - m_b) / l_b ----------
__global__ __launch_bounds__(256) void k2b_weights(
    const float* __restrict__ ws, float* __restrict__ out)
{
    const int idx = blockIdx.x * 256 + threadIdx.x;  // < B_*N_
    const int b = idx >> 12;
    const float lg = ws[OFF_LOGITS + idx];
    out[B_ * H_ + idx] = __expf(lg - ws[OFF_FIN + b]) * ws[OFF_FIN + B_ + b];
}

extern "C" void kernel_launch(void* const* d_in, const int* in_sizes, int n_in,
                              void* d_out, int out_size, void* d_ws, size_t ws_size,
                              hipStream_t stream) {
    const float* v    = (const float*)d_in[0];
    const float* q    = (const float*)d_in[1];
    const float* mask = (const float*)d_in[2];
    const float* Wv   = (const float*)d_in[3];
    const float* bv   = (const float*)d_in[4];
    const float* gv   = (const float*)d_in[5];
    const float* Wq   = (const float*)d_in[6];
    const float* bq   = (const float*)d_in[7];
    const float* gq   = (const float*)d_in[8];
    const float* Wa   = (const float*)d_in[9];
    const float* ba   = (const float*)d_in[10];
    const float* ga   = (const float*)d_in[11];
    float* out = (float*)d_out;
    float* ws  = (float*)d_ws;

    k0a_prep<<<1, 256, 0, stream>>>(Wv, gv, Wq, gq, Wa, ga, ws);
    k0b_qproj<<<B_, 128, 0, stream>>>(q, Wq, bq, bv, ws);
    k1_main<<<dim3(CCH, B_), 256, 0, stream>>>(v, mask, ba, ws);
    k2a_combine<<<B_, 128, 0, stream>>>(ws, out);
    k2b_weights<<<(B_ * N_) / 256, 256, 0, stream>>>(ws, out);
}

// Round 4
// 443.423 us; speedup vs baseline: 1.5327x; 1.0388x over previous
//
#include <hip/hip_runtime.h>

typedef _Float16 half8_t __attribute__((ext_vector_type(8)));
typedef float f32x4 __attribute__((ext_vector_type(4)));

#define B_ 128
#define N_ 4096
#define H_ 128
#define P_ 128
#define CCH 16                       // chunks per batch row
#define ROWS_PER_CHUNK (N_ / CCH)    // 256
#define TILES 4                      // 64-row tiles per chunk (16 rows/wave/iter)

// workspace layout (float offsets)
#define OFF_SCALES 0          // [0]=sv [1]=sq [2]=sa
#define OFF_WA     16         // 128 floats: normalized wa
#define OFF_QPC    256        // B*P floats: q_proj + bq + bv
#define OFF_BPACK  16640      // 16384 f16 = 8192 float slots: MFMA-packed Wv^T
#define OFF_LOGITS 24832      // B*N floats
#define OFF_PART   549120     // B*CCH*132 floats: per-(b,chunk) m,l,o[128],pad2
#define OFF_FIN    819456     // [b]=m_b, [B_+b]=1/l_b

__device__ __forceinline__ float block_reduce_sum(float val, float* red, int tid) {
    red[tid] = val;
    __syncthreads();
    for (int s = 128; s > 0; s >>= 1) {
        if (tid < s) red[tid] += red[tid + s];
        __syncthreads();
    }
    float r = red[0];
    __syncthreads();
    return r;
}

// ---------- K0a: norms, scales, normalized wa, MFMA-packed Wv ----------
__global__ __launch_bounds__(256) void k0a_prep(
    const float* __restrict__ Wv, const float* __restrict__ gv,
    const float* __restrict__ Wq, const float* __restrict__ gq,
    const float* __restrict__ Wa, const float* __restrict__ ga,
    float* __restrict__ ws)
{
    __shared__ float red[256];
    __shared__ float s_sv, s_sa;
    const int tid = threadIdx.x;

    float sv2 = 0.f, sq2 = 0.f, sa2 = 0.f;
    for (int i = tid; i < P_ * H_; i += 256) {
        float x = Wv[i]; sv2 += x * x;
        float y = Wq[i]; sq2 += y * y;
    }
    if (tid < P_) { float z = Wa[tid]; sa2 = z * z; }

    float nv2 = block_reduce_sum(sv2, red, tid);
    float nq2 = block_reduce_sum(sq2, red, tid);
    float na2 = block_reduce_sum(sa2, red, tid);

    if (tid == 0) {
        float sv = gv[0] / sqrtf(nv2);
        float sq = gq[0] / sqrtf(nq2);
        float sa = ga[0] / sqrtf(na2);
        ws[OFF_SCALES + 0] = sv;
        ws[OFF_SCALES + 1] = sq;
        ws[OFF_SCALES + 2] = sa;
        s_sv = sv; s_sa = sa;
    }
    __syncthreads();

    const float sv = s_sv, sa = s_sa;
    // Bpack[s]: s = ((kk*8+pt)*64 + L)*8 + j  ->  Wv[p][h]*sv with
    // p = pt*16 + (L&15), h = kk*32 + (L>>4)*8 + j   (MFMA B-fragment order)
    _Float16* bp = (_Float16*)(ws + OFF_BPACK);
    for (int s = tid; s < 16384; s += 256) {
        int j  = s & 7;
        int L  = (s >> 3) & 63;
        int pt = (s >> 9) & 7;
        int kk = s >> 12;
        int p = pt * 16 + (L & 15);
        int h = kk * 32 + (L >> 4) * 8 + j;
        bp[s] = (_Float16)(Wv[p * H_ + h] * sv);
    }
    if (tid < P_) ws[OFF_WA + tid] = Wa[tid] * sa;
}

// ---------- K0b: q_proj[b][p] = sq*(q[b]·Wq[p]) + bq[p] + bv[p] ----------
__global__ __launch_bounds__(128) void k0b_qproj(
    const float* __restrict__ q, const float* __restrict__ Wq,
    const float* __restrict__ bq, const float* __restrict__ bv,
    float* __restrict__ ws)
{
    const int b = blockIdx.x, p = threadIdx.x;
    const float sq = ws[OFF_SCALES + 1];
    const float* qr = q + b * H_;
    const float* wr = Wq + p * H_;
    float acc = 0.f;
#pragma unroll 8
    for (int h = 0; h < H_; ++h) acc += qr[h] * wr[h];
    ws[OFF_QPC + b * P_ + p] = acc * sq + bq[p] + bv[p];
}

// ---------- K1: one pass over v; wave-private online softmax, zero barriers
// in the K-loop. R4: tile is NOT held in f32 registers across the softmax —
// the o-update re-loads it (L1/L2-hot) via a forced reload (asm memory
// clobber), keeping live VGPRs < 128 (occupancy cliff: waves/SIMD halve
// at vgpr=128; R3's register-held tile crossed it).
__global__ __launch_bounds__(256) void k1_main(
    const float* __restrict__ v, const float* __restrict__ mask,
    const float* __restrict__ ba, float* __restrict__ ws)
{
    const int c = blockIdx.x;   // chunk
    const int b = blockIdx.y;   // batch
    const int tid = threadIdx.x;
    const int lane = tid & 63;
    const int w = tid >> 6;     // wave id 0..3

    __shared__ __align__(16) _Float16 Bl[16384];   // 32 KB packed B-frags
    __shared__ float qpcs[P_];
    __shared__ float was[P_];
    __shared__ float obuf[4][P_];                  // per-wave o partials
    __shared__ float mbuf[4], lbuf[4];

    {
        const uint4* src = (const uint4*)(ws + OFF_BPACK);
        uint4* dst = (uint4*)Bl;
#pragma unroll
        for (int i = 0; i < 8; ++i) dst[tid + i * 256] = src[tid + i * 256];
        if (tid < P_) {
            qpcs[tid] = ws[OFF_QPC + b * P_ + tid];
            was[tid]  = ws[OFF_WA + tid];
        }
    }
    const float ba0 = ba[0];
    __syncthreads();

    const int rloc = lane & 15;        // v-row owned by this lane (A-frag m)
    const int grp  = lane >> 4;        // 16-lane group id 0..3
    const int colb = grp * 8;          // col sub-block within each 32-col slice

    float m_w = -1e30f, l_w = 0.f;
    float o32[32];
#pragma unroll
    for (int j = 0; j < 32; ++j) o32[j] = 0.f;

    for (int it = 0; it < TILES; ++it) {
        const int n0w = c * ROWS_PER_CHUNK + it * 64 + w * 16;

        // ---- load 16x128 tile -> f16 A-frags only (no f32 copy kept)
        const float* vrow = v + ((size_t)b * N_ + n0w + rloc) * H_;
        half8_t af[4];
#pragma unroll
        for (int kk = 0; kk < 4; ++kk) {
            const float4* p4 = (const float4*)(vrow + kk * 32 + colb);
            float4 f0 = p4[0], f1 = p4[1];
            half8_t a;
            a[0] = (_Float16)f0.x; a[1] = (_Float16)f0.y;
            a[2] = (_Float16)f0.z; a[3] = (_Float16)f0.w;
            a[4] = (_Float16)f1.x; a[5] = (_Float16)f1.y;
            a[6] = (_Float16)f1.z; a[7] = (_Float16)f1.w;
            af[kk] = a;
        }

        // ---- v_proj via MFMA + relu·wa partial logits
        float lp[4];
        lp[0] = lp[1] = lp[2] = lp[3] = 0.f;
#pragma unroll
        for (int pt = 0; pt < 8; ++pt) {
            const int p = pt * 16 + rloc;
            const float qv = qpcs[p];
            f32x4 acc = {qv, qv, qv, qv};      // fold q_proj into C init
#pragma unroll
            for (int kk = 0; kk < 4; ++kk) {
                half8_t bf = *(const half8_t*)&Bl[(((kk * 8 + pt) * 64) + lane) * 8];
                acc = __builtin_amdgcn_mfma_f32_16x16x32_f16(af[kk], bf, acc, 0, 0, 0);
            }
            const float wv = was[p];
#pragma unroll
            for (int r = 0; r < 4; ++r)
                lp[r] += fmaxf(acc[r], 0.f) * wv;
        }
        // reduce over the 16 p-cols (lanes differing in bits 0-3)
#pragma unroll
        for (int m = 1; m <= 8; m <<= 1) {
#pragma unroll
            for (int r = 0; r < 4; ++r) lp[r] += __shfl_xor(lp[r], m, 64);
        }
        // lp[r] is now the logit of row (grp*4 + r); add bias + mask
#pragma unroll
        for (int r = 0; r < 4; ++r) {
            const float mk = mask[(size_t)b * N_ + n0w + grp * 4 + r];
            lp[r] += ba0 + (1.0f - mk) * (-10000.0f);
        }

        // transpose: lg_me = logit of row rloc (the row this lane HOLDS)
        const int srcl = (rloc >> 2) << 4;
        float t0 = __shfl(lp[0], srcl, 64);
        float t1 = __shfl(lp[1], srcl, 64);
        float t2 = __shfl(lp[2], srcl, 64);
        float t3 = __shfl(lp[3], srcl, 64);
        float a01 = (rloc & 1) ? t1 : t0;
        float a23 = (rloc & 1) ? t3 : t2;
        float lg_me = (rloc & 2) ? a23 : a01;

        // store logits (lanes 0..15 cover rows n0w..n0w+15, coalesced)
        if (lane < 16) ws[OFF_LOGITS + (size_t)b * N_ + n0w + lane] = lg_me;

        // wave max over its 16 rows
        float mt = fmaxf(fmaxf(lp[0], lp[1]), fmaxf(lp[2], lp[3]));
        mt = fmaxf(mt, __shfl_xor(mt, 16, 64));
        mt = fmaxf(mt, __shfl_xor(mt, 32, 64));

        // wave-private online softmax update
        const float mn = fmaxf(m_w, mt);
        const float alpha = __expf(m_w - mn);
        const float wme = __expf(lg_me - mn);
        float s = wme;
#pragma unroll
        for (int m = 1; m <= 8; m <<= 1) s += __shfl_xor(s, m, 64);
        l_w = l_w * alpha + s;
        m_w = mn;

        // force a genuine re-load of the tile (defeat CSE back into regs):
        // without this the compiler keeps 32 f32 live across the softmax
        // and VGPRs cross the 128 occupancy cliff.
        const float* vrow2 = vrow;
        asm volatile("" : "+v"(vrow2) : : "memory");

        if (alpha != 1.0f) {
#pragma unroll
            for (int j = 0; j < 32; ++j) o32[j] *= alpha;
        }
#pragma unroll
        for (int kk = 0; kk < 4; ++kk) {
            const float4* p4 = (const float4*)(vrow2 + kk * 32 + colb);
            float4 f0 = p4[0], f1 = p4[1];
            o32[kk * 8 + 0] += wme * f0.x; o32[kk * 8 + 1] += wme * f0.y;
            o32[kk * 8 + 2] += wme * f0.z; o32[kk * 8 + 3] += wme * f0.w;
            o32[kk * 8 + 4] += wme * f1.x; o32[kk * 8 + 5] += wme * f1.y;
            o32[kk * 8 + 6] += wme * f1.z; o32[kk * 8 + 7] += wme * f1.w;
        }
    }

    // ---- intra-wave o reduction over the 16 rows (lanes, bits 0-3)
#pragma unroll
    for (int m = 1; m <= 8; m <<= 1) {
#pragma unroll
        for (int j = 0; j < 32; ++j) o32[j] += __shfl_xor(o32[j], m, 64);
    }
    // every lane in group grp now holds o for cols {kk*32 + grp*8 + jj}
    // each lane writes 2 of the 32 values
    {
        const int j0 = rloc * 2;
#pragma unroll
        for (int u = 0; u < 2; ++u) {
            const int j = j0 + u;
            obuf[w][(j >> 3) * 32 + colb + (j & 7)] = o32[j];
        }
        if (lane == 0) { mbuf[w] = m_w; lbuf[w] = l_w; }
    }
    __syncthreads();

    // ---- merge 4 wave partials -> chunk partial
    float* part = ws + OFF_PART + ((size_t)b * CCH + c) * 132;
    if (tid < P_) {
        const float mb = fmaxf(fmaxf(mbuf[0], mbuf[1]), fmaxf(mbuf[2], mbuf[3]));
        float lb = 0.f, oh = 0.f;
#pragma unroll
        for (int ww = 0; ww < 4; ++ww) {
            const float e = __expf(mbuf[ww] - mb);
            lb += e * lbuf[ww];
            oh += e * obuf[ww][tid];
        }
        part[2 + tid] = oh;
        if (tid == 0) { part[0] = mb; part[1] = lb; }
    }
}

// ---------- K2a: combine chunk partials -> att, global m/l ----------
__global__ __launch_bounds__(128) void k2a_combine(
    float* __restrict__ ws, float* __restrict__ out)
{
    const int b = blockIdx.x, h = threadIdx.x;
    const float* part = ws + OFF_PART + (size_t)b * CCH * 132;
    float m = -1e30f;
#pragma unroll
    for (int c = 0; c < CCH; ++c) m = fmaxf(m, part[c * 132]);
    float l = 0.f, a = 0.f;
#pragma unroll
    for (int c = 0; c < CCH; ++c) {
        const float e = __expf(part[c * 132] - m);
        l += e * part[c * 132 + 1];
        a += e * part[c * 132 + 2 + h];
    }
    out[b * H_ + h] = a / l;
    if (h == 0) {
        ws[OFF_FIN + b] = m;
        ws[OFF_FIN + B_ + b] = 1.0f / l;
    }
}

// ---------- K2b: w[b,n] = exp(logit - m_b) / l_b ----------
__global__ __launch_bounds__(256) void k2b_weights(
    const float* __restrict__ ws, float* __restrict__ out)
{
    const int idx = blockIdx.x * 256 + threadIdx.x;  // < B_*N_
    const int b = idx >> 12;
    const float lg = ws[OFF_LOGITS + idx];
    out[B_ * H_ + idx] = __expf(lg - ws[OFF_FIN + b]) * ws[OFF_FIN + B_ + b];
}

extern "C" void kernel_launch(void* const* d_in, const int* in_sizes, int n_in,
                              void* d_out, int out_size, void* d_ws, size_t ws_size,
                              hipStream_t stream) {
    const float* v    = (const float*)d_in[0];
    const float* q    = (const float*)d_in[1];
    const float* mask = (const float*)d_in[2];
    const float* Wv   = (const float*)d_in[3];
    const float* bv   = (const float*)d_in[4];
    const float* gv   = (const float*)d_in[5];
    const float* Wq   = (const float*)d_in[6];
    const float* bq   = (const float*)d_in[7];
    const float* gq   = (const float*)d_in[8];
    const float* Wa   = (const float*)d_in[9];
    const float* ba   = (const float*)d_in[10];
    const float* ga   = (const float*)d_in[11];
    float* out = (float*)d_out;
    float* ws  = (float*)d_ws;

    k0a_prep<<<1, 256, 0, stream>>>(Wv, gv, Wq, gq, Wa, ga, ws);
    k0b_qproj<<<B_, 128, 0, stream>>>(q, Wq, bq, bv, ws);
    k1_main<<<dim3(CCH, B_), 256, 0, stream>>>(v, mask, ba, ws);
    k2a_combine<<<B_, 128, 0, stream>>>(ws, out);
    k2b_weights<<<(B_ * N_) / 256, 256, 0, stream>>>(ws, out);
}

// Round 5
// 434.265 us; speedup vs baseline: 1.5650x; 1.0211x over previous
//
#include <hip/hip_runtime.h>

typedef _Float16 half8_t __attribute__((ext_vector_type(8)));
typedef float f32x4 __attribute__((ext_vector_type(4)));

#define B_ 128
#define N_ 4096
#define H_ 128
#define P_ 128
#define CCH 8                        // chunks per batch row -> 1024 blocks = 4/CU exactly
#define ROWS_PER_CHUNK (N_ / CCH)    // 512
#define TILES (ROWS_PER_CHUNK / 64)  // 8 iterations of 64 rows (16/wave)

// workspace layout (float offsets)
#define OFF_SCALES 0          // [0]=sv [1]=sq [2]=sa
#define OFF_WA     16         // 128 floats: normalized wa
#define OFF_QPC    256        // B*P floats: q_proj + bq + bv
#define OFF_BPACK  16640      // 16384 f16 = 8192 float slots: MFMA-packed Wv^T
#define OFF_LOGITS 24832      // B*N floats
#define OFF_PART   549120     // B*CCH*132 floats: per-(b,chunk) m,l,o[128],pad2
#define OFF_FIN    819456     // [b]=m_b, [B_+b]=1/l_b

__device__ __forceinline__ float block_reduce_sum(float val, float* red, int tid) {
    red[tid] = val;
    __syncthreads();
    for (int s = 128; s > 0; s >>= 1) {
        if (tid < s) red[tid] += red[tid + s];
        __syncthreads();
    }
    float r = red[0];
    __syncthreads();
    return r;
}

// ---------- K0a: norms, scales, normalized wa, MFMA-packed Wv ----------
__global__ __launch_bounds__(256) void k0a_prep(
    const float* __restrict__ Wv, const float* __restrict__ gv,
    const float* __restrict__ Wq, const float* __restrict__ gq,
    const float* __restrict__ Wa, const float* __restrict__ ga,
    float* __restrict__ ws)
{
    __shared__ float red[256];
    __shared__ float s_sv, s_sa;
    const int tid = threadIdx.x;

    float sv2 = 0.f, sq2 = 0.f, sa2 = 0.f;
    for (int i = tid; i < P_ * H_; i += 256) {
        float x = Wv[i]; sv2 += x * x;
        float y = Wq[i]; sq2 += y * y;
    }
    if (tid < P_) { float z = Wa[tid]; sa2 = z * z; }

    float nv2 = block_reduce_sum(sv2, red, tid);
    float nq2 = block_reduce_sum(sq2, red, tid);
    float na2 = block_reduce_sum(sa2, red, tid);

    if (tid == 0) {
        float sv = gv[0] / sqrtf(nv2);
        float sq = gq[0] / sqrtf(nq2);
        float sa = ga[0] / sqrtf(na2);
        ws[OFF_SCALES + 0] = sv;
        ws[OFF_SCALES + 1] = sq;
        ws[OFF_SCALES + 2] = sa;
        s_sv = sv; s_sa = sa;
    }
    __syncthreads();

    const float sv = s_sv, sa = s_sa;
    // Bpack[s]: s = ((kk*8+pt)*64 + L)*8 + j  ->  Wv[p][h]*sv with
    // p = pt*16 + (L&15), h = kk*32 + (L>>4)*8 + j   (MFMA B-fragment order)
    _Float16* bp = (_Float16*)(ws + OFF_BPACK);
    for (int s = tid; s < 16384; s += 256) {
        int j  = s & 7;
        int L  = (s >> 3) & 63;
        int pt = (s >> 9) & 7;
        int kk = s >> 12;
        int p = pt * 16 + (L & 15);
        int h = kk * 32 + (L >> 4) * 8 + j;
        bp[s] = (_Float16)(Wv[p * H_ + h] * sv);
    }
    if (tid < P_) ws[OFF_WA + tid] = Wa[tid] * sa;
}

// ---------- K0b: q_proj[b][p] = sq*(q[b]·Wq[p]) + bq[p] + bv[p] ----------
__global__ __launch_bounds__(128) void k0b_qproj(
    const float* __restrict__ q, const float* __restrict__ Wq,
    const float* __restrict__ bq, const float* __restrict__ bv,
    float* __restrict__ ws)
{
    const int b = blockIdx.x, p = threadIdx.x;
    const float sq = ws[OFF_SCALES + 1];
    const float* qr = q + b * H_;
    const float* wr = Wq + p * H_;
    float acc = 0.f;
#pragma unroll 8
    for (int h = 0; h < H_; ++h) acc += qr[h] * wr[h];
    ws[OFF_QPC + b * P_ + p] = acc * sq + bq[p] + bv[p];
}

// ---------- K1: one pass over v; wave-private online softmax, zero barriers
// in the K-loop. R5: v is read from HBM EXACTLY ONCE — the o-update converts
// the f16 A-fragments back to f32 (32 v_cvt, no memory) instead of reloading
// (R4's "L1-hot" reload actually thrashed the 4 MB per-XCD L2: 128 resident
// blocks x 32 KB in-flight tiles = 4 MB). CCH=8 -> 1024 blocks = exactly
// 4 blocks/CU (LDS cap): single co-resident batch, 8 iters to amortize
// the 32 KB B-stage prologue.
__global__ __launch_bounds__(256) void k1_main(
    const float* __restrict__ v, const float* __restrict__ mask,
    const float* __restrict__ ba, float* __restrict__ ws)
{
    const int c = blockIdx.x;   // chunk
    const int b = blockIdx.y;   // batch
    const int tid = threadIdx.x;
    const int lane = tid & 63;
    const int w = tid >> 6;     // wave id 0..3

    __shared__ __align__(16) _Float16 Bl[16384];   // 32 KB packed B-frags
    __shared__ float qpcs[P_];
    __shared__ float was[P_];
    __shared__ float smask[ROWS_PER_CHUNK];        // 2 KB chunk mask
    __shared__ float obuf[4][P_];                  // per-wave o partials
    __shared__ float mbuf[4], lbuf[4];

    {
        const uint4* src = (const uint4*)(ws + OFF_BPACK);
        uint4* dst = (uint4*)Bl;
#pragma unroll
        for (int i = 0; i < 8; ++i) dst[tid + i * 256] = src[tid + i * 256];
        if (tid < P_) {
            qpcs[tid] = ws[OFF_QPC + b * P_ + tid];
            was[tid]  = ws[OFF_WA + tid];
        }
#pragma unroll
        for (int i = 0; i < ROWS_PER_CHUNK / 256; ++i)
            smask[tid + i * 256] = mask[(size_t)b * N_ + c * ROWS_PER_CHUNK + tid + i * 256];
    }
    const float ba0 = ba[0];
    __syncthreads();

    const int rloc = lane & 15;        // v-row owned by this lane (A-frag m)
    const int grp  = lane >> 4;        // 16-lane group id 0..3
    const int colb = grp * 8;          // col sub-block within each 32-col slice

    float m_w = -1e30f, l_w = 0.f;
    float o32[32];
#pragma unroll
    for (int j = 0; j < 32; ++j) o32[j] = 0.f;

    for (int it = 0; it < TILES; ++it) {
        const int r0 = it * 64 + w * 16;                 // row offset in chunk
        const int n0w = c * ROWS_PER_CHUNK + r0;         // global row

        // ---- load 16x128 tile -> f16 A-frags (sole HBM touch of v)
        const float* vrow = v + ((size_t)b * N_ + n0w + rloc) * H_;
        half8_t af[4];
#pragma unroll
        for (int kk = 0; kk < 4; ++kk) {
            const float4* p4 = (const float4*)(vrow + kk * 32 + colb);
            float4 f0 = p4[0], f1 = p4[1];
            half8_t a;
            a[0] = (_Float16)f0.x; a[1] = (_Float16)f0.y;
            a[2] = (_Float16)f0.z; a[3] = (_Float16)f0.w;
            a[4] = (_Float16)f1.x; a[5] = (_Float16)f1.y;
            a[6] = (_Float16)f1.z; a[7] = (_Float16)f1.w;
            af[kk] = a;
        }

        // ---- v_proj via MFMA + relu·wa partial logits
        float lp[4];
        lp[0] = lp[1] = lp[2] = lp[3] = 0.f;
#pragma unroll
        for (int pt = 0; pt < 8; ++pt) {
            const int p = pt * 16 + rloc;
            const float qv = qpcs[p];
            f32x4 acc = {qv, qv, qv, qv};      // fold q_proj into C init
#pragma unroll
            for (int kk = 0; kk < 4; ++kk) {
                half8_t bf = *(const half8_t*)&Bl[(((kk * 8 + pt) * 64) + lane) * 8];
                acc = __builtin_amdgcn_mfma_f32_16x16x32_f16(af[kk], bf, acc, 0, 0, 0);
            }
            const float wv = was[p];
#pragma unroll
            for (int r = 0; r < 4; ++r)
                lp[r] += fmaxf(acc[r], 0.f) * wv;
        }
        // reduce over the 16 p-cols (lanes differing in bits 0-3)
#pragma unroll
        for (int m = 1; m <= 8; m <<= 1) {
#pragma unroll
            for (int r = 0; r < 4; ++r) lp[r] += __shfl_xor(lp[r], m, 64);
        }
        // lp[r] is now the logit of row (grp*4 + r); add bias + mask (LDS)
#pragma unroll
        for (int r = 0; r < 4; ++r) {
            const float mk = smask[r0 + grp * 4 + r];
            lp[r] += ba0 + (1.0f - mk) * (-10000.0f);
        }

        // transpose: lg_me = logit of row rloc (the row this lane HOLDS)
        const int srcl = (rloc >> 2) << 4;
        float t0 = __shfl(lp[0], srcl, 64);
        float t1 = __shfl(lp[1], srcl, 64);
        float t2 = __shfl(lp[2], srcl, 64);
        float t3 = __shfl(lp[3], srcl, 64);
        float a01 = (rloc & 1) ? t1 : t0;
        float a23 = (rloc & 1) ? t3 : t2;
        float lg_me = (rloc & 2) ? a23 : a01;

        // store logits (lanes 0..15 cover rows n0w..n0w+15, coalesced)
        if (lane < 16) ws[OFF_LOGITS + (size_t)b * N_ + n0w + lane] = lg_me;

        // wave max over its 16 rows
        float mt = fmaxf(fmaxf(lp[0], lp[1]), fmaxf(lp[2], lp[3]));
        mt = fmaxf(mt, __shfl_xor(mt, 16, 64));
        mt = fmaxf(mt, __shfl_xor(mt, 32, 64));

        // wave-private online softmax update
        const float mn = fmaxf(m_w, mt);
        const float alpha = __expf(m_w - mn);
        const float wme = __expf(lg_me - mn);
        float s = wme;
#pragma unroll
        for (int m = 1; m <= 8; m <<= 1) s += __shfl_xor(s, m, 64);
        l_w = l_w * alpha + s;
        m_w = mn;

        if (alpha != 1.0f) {
#pragma unroll
            for (int j = 0; j < 32; ++j) o32[j] *= alpha;
        }
        // o-update from the registers we already hold (f16 -> f32 cvt)
#pragma unroll
        for (int kk = 0; kk < 4; ++kk) {
#pragma unroll
            for (int j = 0; j < 8; ++j)
                o32[kk * 8 + j] += wme * (float)af[kk][j];
        }
    }

    // ---- intra-wave o reduction over the 16 rows (lanes, bits 0-3)
#pragma unroll
    for (int m = 1; m <= 8; m <<= 1) {
#pragma unroll
        for (int j = 0; j < 32; ++j) o32[j] += __shfl_xor(o32[j], m, 64);
    }
    // every lane in group grp now holds o for cols {kk*32 + grp*8 + jj}
    // each lane writes 2 of the 32 values
    {
        const int j0 = rloc * 2;
#pragma unroll
        for (int u = 0; u < 2; ++u) {
            const int j = j0 + u;
            obuf[w][(j >> 3) * 32 + colb + (j & 7)] = o32[j];
        }
        if (lane == 0) { mbuf[w] = m_w; lbuf[w] = l_w; }
    }
    __syncthreads();

    // ---- merge 4 wave partials -> chunk partial
    float* part = ws + OFF_PART + ((size_t)b * CCH + c) * 132;
    if (tid < P_) {
        const float mb = fmaxf(fmaxf(mbuf[0], mbuf[1]), fmaxf(mbuf[2], mbuf[3]));
        float lb = 0.f, oh = 0.f;
#pragma unroll
        for (int ww = 0; ww < 4; ++ww) {
            const float e = __expf(mbuf[ww] - mb);
            lb += e * lbuf[ww];
            oh += e * obuf[ww][tid];
        }
        part[2 + tid] = oh;
        if (tid == 0) { part[0] = mb; part[1] = lb; }
    }
}

// ---------- K2a: combine chunk partials -> att, global m/l ----------
__global__ __launch_bounds__(128) void k2a_combine(
    float* __restrict__ ws, float* __restrict__ out)
{
    const int b = blockIdx.x, h = threadIdx.x;
    const float* part = ws + OFF_PART + (size_t)b * CCH * 132;
    float m = -1e30f;
#pragma unroll
    for (int c = 0; c < CCH; ++c) m = fmaxf(m, part[c * 132]);
    float l = 0.f, a = 0.f;
#pragma unroll
    for (int c = 0; c < CCH; ++c) {
        const float e = __expf(part[c * 132] - m);
        l += e * part[c * 132 + 1];
        a += e * part[c * 132 + 2 + h];
    }
    out[b * H_ + h] = a / l;
    if (h == 0) {
        ws[OFF_FIN + b] = m;
        ws[OFF_FIN + B_ + b] = 1.0f / l;
    }
}

// ---------- K2b: w[b,n] = exp(logit - m_b) / l_b ----------
__global__ __launch_bounds__(256) void k2b_weights(
    const float* __restrict__ ws, float* __restrict__ out)
{
    const int idx = blockIdx.x * 256 + threadIdx.x;  // < B_*N_
    const int b = idx >> 12;
    const float lg = ws[OFF_LOGITS + idx];
    out[B_ * H_ + idx] = __expf(lg - ws[OFF_FIN + b]) * ws[OFF_FIN + B_ + b];
}

extern "C" void kernel_launch(void* const* d_in, const int* in_sizes, int n_in,
                              void* d_out, int out_size, void* d_ws, size_t ws_size,
                              hipStream_t stream) {
    const float* v    = (const float*)d_in[0];
    const float* q    = (const float*)d_in[1];
    const float* mask = (const float*)d_in[2];
    const float* Wv   = (const float*)d_in[3];
    const float* bv   = (const float*)d_in[4];
    const float* gv   = (const float*)d_in[5];
    const float* Wq   = (const float*)d_in[6];
    const float* bq   = (const float*)d_in[7];
    const float* gq   = (const float*)d_in[8];
    const float* Wa   = (const float*)d_in[9];
    const float* ba   = (const float*)d_in[10];
    const float* ga   = (const float*)d_in[11];
    float* out = (float*)d_out;
    float* ws  = (float*)d_ws;

    k0a_prep<<<1, 256, 0, stream>>>(Wv, gv, Wq, gq, Wa, ga, ws);
    k0b_qproj<<<B_, 128, 0, stream>>>(q, Wq, bq, bv, ws);
    k1_main<<<dim3(CCH, B_), 256, 0, stream>>>(v, mask, ba, ws);
    k2a_combine<<<B_, 128, 0, stream>>>(ws, out);
    k2b_weights<<<(B_ * N_) / 256, 256, 0, stream>>>(ws, out);
}